// Round 1
// baseline (142.392 us; speedup 1.0000x reference)
//
#include <hip/hip_runtime.h>
#include <math.h>

#define NTHREADS 1024
#define MAXN 4096
#define PER 4          // MAXN / NTHREADS
#define DETS 100

__global__ __launch_bounds__(NTHREADS) void postproc_kernel(
    const float* __restrict__ logits,   // (B,N,2)
    const float* __restrict__ regr,     // (B,N,8)
    const float* __restrict__ props,    // (B,N,4)
    float* __restrict__ out,            // (B,100,5) ++ (B,100) labels ++ (B,100) valid, all as f32
    int B, int N)
{
#pragma clang fp contract(off)
    const int b   = blockIdx.x;
    const int tid = threadIdx.x;

    __shared__ unsigned long long keys[MAXN];
    __shared__ float sc[MAXN];
    __shared__ float slot[6];   // x1,y1,x2,y2,area,keepflag

    const float* lg = logits + (size_t)b * N * 2;
    const float* rg = regr   + (size_t)b * N * 8;
    const float* pp = props  + (size_t)b * N * 4;

    // ---------------- Phase A: scores + sort keys ----------------
    for (int a = tid; a < MAXN; a += NTHREADS) {
        unsigned long long key;
        float score = 0.0f;
        if (a < N) {
            float l0 = lg[a * 2 + 0];
            float l1 = lg[a * 2 + 1];
            // replicate softmax(logits)[:,1] in float32 op order; exp correctly rounded
            float m  = fmaxf(l0, l1);
            float e0 = (float)exp((double)(l0 - m));
            float e1 = (float)exp((double)(l1 - m));
            float s  = e1 / (e0 + e1);
            score = s;
            bool valid = score > 0.05f;
            float f = valid ? score : -1e30f;
            unsigned u = __float_as_uint(f);
            u = (u & 0x80000000u) ? ~u : (u | 0x80000000u);  // monotone float->uint
            key = ((unsigned long long)(~u) << 32) | (unsigned)a; // asc sort => score desc, idx asc
        } else {
            key = 0xFFFFFFFFFFFFFFFFull;  // pad to end
        }
        keys[a] = key;
        sc[a]   = score;
    }

    // ---------------- Phase B: bitonic ascending sort of keys ----------------
    for (unsigned k = 2; k <= MAXN; k <<= 1) {
        for (unsigned j = k >> 1; j > 0; j >>= 1) {
            __syncthreads();
            for (unsigned t = tid; t < MAXN / 2; t += NTHREADS) {
                unsigned i   = 2u * t - (t & (j - 1u));
                unsigned ixj = i | j;
                unsigned long long a = keys[i];
                unsigned long long c = keys[ixj];
                bool up = ((i & k) == 0u);
                if ((a > c) == up) { keys[i] = c; keys[ixj] = a; }
            }
        }
    }
    __syncthreads();

    // ---------------- Phase C: gather sorted entries, decode boxes ----------------
    float bx1[PER], by1[PER], bx2[PER], by2[PER], barea[PER], bscore[PER];
    int keepf[PER];
    const float CLIPV = (float)4.135166556742356;  // log(1000/16)

    for (int t = 0; t < PER; ++t) {
        int r = PER * tid + t;
        bx1[t] = by1[t] = bx2[t] = by2[t] = 0.0f;
        barea[t] = 0.0f; bscore[t] = 0.0f; keepf[t] = 0;
        int idx = (int)(keys[r] & 0xFFFFFFFFull);
        if (r < N && idx < N) {
            float p0 = pp[idx * 4 + 0], p1 = pp[idx * 4 + 1];
            float p2 = pp[idx * 4 + 2], p3 = pp[idx * 4 + 3];
            float r4 = rg[idx * 8 + 4], r5 = rg[idx * 8 + 5];
            float r6 = rg[idx * 8 + 6], r7 = rg[idx * 8 + 7];
            // decode, replicating reference float32 op order (no FMA)
            float w  = (p2 - p0) + 1.0f;
            float h  = (p3 - p1) + 1.0f;
            float cx = p0 + 0.5f * w;
            float cy = p1 + 0.5f * h;
            float dx = r4 / 10.0f;
            float dy = r5 / 10.0f;
            float dw = fminf(r6 / 5.0f, CLIPV);
            float dh = fminf(r7 / 5.0f, CLIPV);
            float pcx = dx * w + cx;
            float pcy = dy * h + cy;
            float ew = (float)exp((double)dw);
            float eh = (float)exp((double)dh);
            float pw = ew * w;
            float ph = eh * h;
            float x1 = pcx - 0.5f * pw;
            float y1 = pcy - 0.5f * ph;
            float x2 = (pcx + 0.5f * pw) - 1.0f;
            float y2 = (pcy + 0.5f * ph) - 1.0f;
            x1 = fminf(fmaxf(x1, 0.0f), 511.0f);
            y1 = fminf(fmaxf(y1, 0.0f), 511.0f);
            x2 = fminf(fmaxf(x2, 0.0f), 511.0f);
            y2 = fminf(fmaxf(y2, 0.0f), 511.0f);
            bx1[t] = x1; by1[t] = y1; bx2[t] = x2; by2[t] = y2;
            barea[t]  = ((x2 - x1) + 1.0f) * ((y2 - y1) + 1.0f);
            bscore[t] = sc[idx];
            keepf[t]  = (bscore[t] > 0.05f) ? 1 : 0;
        }
    }

    float* obox = out + (size_t)b * DETS * 5;
    float* olab = out + (size_t)B * DETS * 5 + (size_t)b * DETS;
    float* oval = out + (size_t)B * DETS * 5 + (size_t)B * DETS + (size_t)b * DETS;

    // ---------------- greedy NMS with early exit at DETS keepers ----------------
    int kept = 0;
    for (int i = 0; i < N && kept < DETS; ++i) {
        __syncthreads();              // protect slot reuse from previous iteration
        if ((i >> 2) == tid) {        // owner of rank i (PER==4)
            int t = i & (PER - 1);
            slot[5] = keepf[t] ? 1.0f : 0.0f;
            if (keepf[t]) {
                slot[0] = bx1[t]; slot[1] = by1[t];
                slot[2] = bx2[t]; slot[3] = by2[t];
                slot[4] = barea[t];
                float* o = obox + kept * 5;
                o[0] = bx1[t]; o[1] = by1[t]; o[2] = bx2[t]; o[3] = by2[t];
                o[4] = bscore[t];
                olab[kept] = 1.0f;
                oval[kept] = 1.0f;
            }
        }
        __syncthreads();
        if (slot[5] != 0.0f) {
            float sx1 = slot[0], sy1 = slot[1], sx2 = slot[2], sy2 = slot[3];
            float sa  = slot[4];
            for (int t = 0; t < PER; ++t) {
                int r = PER * tid + t;
                if (r > i && keepf[t]) {
                    float xx1 = fmaxf(bx1[t], sx1);
                    float yy1 = fmaxf(by1[t], sy1);
                    float xx2 = fminf(bx2[t], sx2);
                    float yy2 = fminf(by2[t], sy2);
                    float iw  = fmaxf((xx2 - xx1) + 1.0f, 0.0f);
                    float ih  = fmaxf((yy2 - yy1) + 1.0f, 0.0f);
                    float inter = iw * ih;
                    float iou = inter / ((sa + barea[t]) - inter);
                    if (iou > 0.5f) keepf[t] = 0;
                }
            }
            kept++;
        }
    }

    // ---------------- zero-fill remaining output rows ----------------
    for (int c = kept + (int)tid; c < DETS; c += NTHREADS) {
        float* o = obox + c * 5;
        o[0] = 0.0f; o[1] = 0.0f; o[2] = 0.0f; o[3] = 0.0f; o[4] = 0.0f;
        olab[c] = 0.0f;
        oval[c] = 0.0f;
    }
}

extern "C" void kernel_launch(void* const* d_in, const int* in_sizes, int n_in,
                              void* d_out, int out_size, void* d_ws, size_t ws_size,
                              hipStream_t stream) {
    (void)d_ws; (void)ws_size; (void)n_in;
    const float* logits = (const float*)d_in[0];
    const float* regr   = (const float*)d_in[1];
    const float* props  = (const float*)d_in[2];
    float* out = (float*)d_out;

    int B = out_size / 700;          // (100*5 + 100 + 100) per image
    if (B < 1) B = 1;
    int N = in_sizes[0] / (2 * B);   // logits = B*N*2

    postproc_kernel<<<B, NTHREADS, 0, stream>>>(logits, regr, props, out, B, N);
}

// Round 2
// 52.476 us; speedup vs baseline: 2.7134x; 2.7134x over previous
//
#include <hip/hip_runtime.h>
#include <math.h>

#define NTHREADS 1024
#define MAXN 4096
#define DETS 100

__device__ __forceinline__ unsigned long long shfl_xor64(unsigned long long x, int m) {
    int lo = __shfl_xor((int)(unsigned)x, m, 64);
    int hi = __shfl_xor((int)(unsigned)(x >> 32), m, 64);
    return ((unsigned long long)(unsigned)hi << 32) | (unsigned)lo;
}
__device__ __forceinline__ unsigned long long shfl_bc64(unsigned long long x, int src) {
    int lo = __shfl((int)(unsigned)x, src, 64);
    int hi = __shfl((int)(unsigned)(x >> 32), src, 64);
    return ((unsigned long long)(unsigned)hi << 32) | (unsigned)lo;
}

__device__ __forceinline__ float iou_f(float ax1, float ay1, float ax2, float ay2, float aar,
                                       float bx1, float by1, float bx2, float by2, float bar) {
#pragma clang fp contract(off)
    float xx1 = fmaxf(ax1, bx1), yy1 = fmaxf(ay1, by1);
    float xx2 = fminf(ax2, bx2), yy2 = fminf(ay2, by2);
    float iw = fmaxf((xx2 - xx1) + 1.0f, 0.0f);
    float ih = fmaxf((yy2 - yy1) + 1.0f, 0.0f);
    float inter = iw * ih;
    return inter / ((aar + bar) - inter);
}

__global__ __launch_bounds__(NTHREADS) void postproc_kernel(
    const float* __restrict__ logits,   // (B,N,2)
    const float* __restrict__ regr,     // (B,N,8)
    const float* __restrict__ props,    // (B,N,4)
    float* __restrict__ out,            // (B,100,5) ++ (B,100) ++ (B,100)
    int B, int N)
{
#pragma clang fp contract(off)
    const int b   = blockIdx.x;
    const int tid = threadIdx.x;
    const int base = tid * 4;

    __shared__ unsigned long long keys[MAXN];   // 32 KB
    __shared__ float sc[MAXN];                  // 16 KB
    __shared__ float tb[6][64];                 // tile boxes: x1,y1,x2,y2,area,score
    __shared__ float kb[5][DETS + 64];          // kept boxes: x1,y1,x2,y2,area
    __shared__ unsigned tmask[64][2];           // intra-tile suppression bitmask rows
    __shared__ unsigned supk[64];               // suppressed-by-kept / invalid flags
    __shared__ int keptCount;

    const float* lg = logits + (size_t)b * N * 2;
    const float* rg = regr   + (size_t)b * N * 8;
    const float* pp = props  + (size_t)b * N * 4;

    // ---------------- Phase A: scores + sort keys (registers) ----------------
    unsigned long long v[4];
#pragma unroll
    for (int s = 0; s < 4; ++s) {
        int a = base + s;
        unsigned long long key;
        float score = 0.0f;
        if (a < N) {
            float l0 = lg[a * 2 + 0];
            float l1 = lg[a * 2 + 1];
            float m  = fmaxf(l0, l1);
            float e0 = (float)exp((double)(l0 - m));
            float e1 = (float)exp((double)(l1 - m));
            score = e1 / (e0 + e1);
            float f = (score > 0.05f) ? score : -1e30f;
            unsigned u = __float_as_uint(f);
            u = (u & 0x80000000u) ? ~u : (u | 0x80000000u);   // monotone float->uint
            key = ((unsigned long long)(~u) << 32) | (unsigned)a;  // asc => score desc, idx asc
        } else {
            key = 0xFFFFFFFFFFFFFFFFull;
        }
        v[s] = key;
        sc[a] = score;   // base+s < MAXN always
    }

    // ---------------- Phase B: hybrid bitonic sort (regs + shfl + LDS) ----------------
    for (unsigned k = 2; k <= MAXN; k <<= 1) {
        for (unsigned j = k >> 1; j > 0; j >>= 1) {
            if (j >= 256) {
                // cross-wave: stage through LDS
                __syncthreads();
                keys[base + 0] = v[0]; keys[base + 1] = v[1];
                keys[base + 2] = v[2]; keys[base + 3] = v[3];
                __syncthreads();
                bool up = ((base & (int)k) == 0);
                bool keepmin = (((base & (int)j) == 0) == up);
                int pb = base ^ (int)j;
#pragma unroll
                for (int s = 0; s < 4; ++s) {
                    unsigned long long p = keys[pb + s];
                    unsigned long long mn = v[s] < p ? v[s] : p;
                    unsigned long long mx = v[s] < p ? p : v[s];
                    v[s] = keepmin ? mn : mx;
                }
            } else if (j >= 4) {
                // intra-wave: shfl exchange
                bool up = ((base & (int)k) == 0);
                bool keepmin = (((base & (int)j) == 0) == up);
                int m = (int)(j >> 2);
#pragma unroll
                for (int s = 0; s < 4; ++s) {
                    unsigned long long p = shfl_xor64(v[s], m);
                    unsigned long long mn = v[s] < p ? v[s] : p;
                    unsigned long long mx = v[s] < p ? p : v[s];
                    v[s] = keepmin ? mn : mx;
                }
            } else if (j == 2) {
                bool up = ((base & (int)k) == 0);
                {
                    unsigned long long a0 = v[0], b0 = v[2];
                    unsigned long long mn = a0 < b0 ? a0 : b0, mx = a0 < b0 ? b0 : a0;
                    v[0] = up ? mn : mx; v[2] = up ? mx : mn;
                }
                {
                    unsigned long long a0 = v[1], b0 = v[3];
                    unsigned long long mn = a0 < b0 ? a0 : b0, mx = a0 < b0 ? b0 : a0;
                    v[1] = up ? mn : mx; v[3] = up ? mx : mn;
                }
            } else { // j == 1
                bool up0 = (((base + 0) & (int)k) == 0);
                bool up1 = (((base + 2) & (int)k) == 0);
                {
                    unsigned long long a0 = v[0], b0 = v[1];
                    unsigned long long mn = a0 < b0 ? a0 : b0, mx = a0 < b0 ? b0 : a0;
                    v[0] = up0 ? mn : mx; v[1] = up0 ? mx : mn;
                }
                {
                    unsigned long long a0 = v[2], b0 = v[3];
                    unsigned long long mn = a0 < b0 ? a0 : b0, mx = a0 < b0 ? b0 : a0;
                    v[2] = up1 ? mn : mx; v[3] = up1 ? mx : mn;
                }
            }
        }
    }
    __syncthreads();
    keys[base + 0] = v[0]; keys[base + 1] = v[1];
    keys[base + 2] = v[2]; keys[base + 3] = v[3];
    __syncthreads();

    // ---------------- Phase C: tiled greedy NMS ----------------
    float* obox = out + (size_t)b * DETS * 5;
    float* olab = out + (size_t)B * DETS * 5 + (size_t)b * DETS;
    float* oval = out + (size_t)B * DETS * 5 + (size_t)B * DETS + (size_t)b * DETS;
    const float CLIPV = (float)4.135166556742356;   // log(1000/16)

    int kept = 0;
    for (int i0 = 0; i0 < N && kept < DETS; i0 += 64) {
        // decode this tile's candidates (only tiles actually scanned get decoded)
        if (tid < 64) {
            int r = i0 + tid;
            bool valid = false;
            if (r < N) {
                unsigned long long key = keys[r];
                unsigned idx = (unsigned)(key & 0xFFFFFFFFull);
                if (idx < (unsigned)N) {
                    float score = sc[idx];
                    if (score > 0.05f) {
                        valid = true;
                        float p0 = pp[idx * 4 + 0], p1 = pp[idx * 4 + 1];
                        float p2 = pp[idx * 4 + 2], p3 = pp[idx * 4 + 3];
                        float r4 = rg[idx * 8 + 4], r5 = rg[idx * 8 + 5];
                        float r6 = rg[idx * 8 + 6], r7 = rg[idx * 8 + 7];
                        float w  = (p2 - p0) + 1.0f;
                        float h  = (p3 - p1) + 1.0f;
                        float cx = p0 + 0.5f * w;
                        float cy = p1 + 0.5f * h;
                        float dx = r4 / 10.0f;
                        float dy = r5 / 10.0f;
                        float dw = fminf(r6 / 5.0f, CLIPV);
                        float dh = fminf(r7 / 5.0f, CLIPV);
                        float pcx = dx * w + cx;
                        float pcy = dy * h + cy;
                        float ew = (float)exp((double)dw);
                        float eh = (float)exp((double)dh);
                        float pw = ew * w;
                        float ph = eh * h;
                        float x1 = pcx - 0.5f * pw;
                        float y1 = pcy - 0.5f * ph;
                        float x2 = (pcx + 0.5f * pw) - 1.0f;
                        float y2 = (pcy + 0.5f * ph) - 1.0f;
                        x1 = fminf(fmaxf(x1, 0.0f), 511.0f);
                        y1 = fminf(fmaxf(y1, 0.0f), 511.0f);
                        x2 = fminf(fmaxf(x2, 0.0f), 511.0f);
                        y2 = fminf(fmaxf(y2, 0.0f), 511.0f);
                        tb[0][tid] = x1; tb[1][tid] = y1;
                        tb[2][tid] = x2; tb[3][tid] = y2;
                        tb[4][tid] = ((x2 - x1) + 1.0f) * ((y2 - y1) + 1.0f);
                        tb[5][tid] = score;
                    }
                }
            }
            supk[tid] = valid ? 0u : 1u;
        } else if (tid < 192) {
            int q = tid - 64;
            tmask[q >> 1][q & 1] = 0u;
        }
        __syncthreads();

        // candidate-vs-kept suppression (64 candidates x 16 slices of kept list)
        {
            int c = tid & 63, sl = tid >> 6;
            if (supk[c] == 0u) {
                float x1 = tb[0][c], y1 = tb[1][c], x2 = tb[2][c], y2 = tb[3][c], ar = tb[4][c];
                for (int s = sl; s < kept; s += 16) {
                    float iou = iou_f(kb[0][s], kb[1][s], kb[2][s], kb[3][s], kb[4][s],
                                      x1, y1, x2, y2, ar);
                    if (iou > 0.5f) { supk[c] = 1u; break; }
                }
            }
        }
        // intra-tile 64x64 suppression bitmask (row i suppresses j>i if IoU>0.5)
        {
            int i = tid >> 4, jb = (tid & 15) << 2;
            float x1 = tb[0][i], y1 = tb[1][i], x2 = tb[2][i], y2 = tb[3][i], ar = tb[4][i];
            unsigned nib = 0;
#pragma unroll
            for (int u = 0; u < 4; ++u) {
                int j = jb + u;
                if (j > i) {
                    float iou = iou_f(x1, y1, x2, y2, ar,
                                      tb[0][j], tb[1][j], tb[2][j], tb[3][j], tb[4][j]);
                    if (iou > 0.5f) nib |= (1u << u);
                }
            }
            if (nib) atomicOr(&tmask[i][jb >> 5], nib << (jb & 31));
        }
        __syncthreads();

        // wave 0: serial greedy resolve over the 64 candidates (in-register, no barriers)
        if (tid < 64) {
            int l = tid;
            unsigned long long row = ((unsigned long long)tmask[l][1] << 32) | tmask[l][0];
            int alive = supk[l] ? 0 : 1;
            for (int c = 0; c < 64; ++c) {
                int ac = __shfl(alive, c, 64);
                unsigned long long rc = shfl_bc64(row, c);
                if (ac && ((rc >> l) & 1ull)) alive = 0;
            }
            unsigned long long am = __ballot(alive);
            int rank = kept + (int)__popcll(am & ((1ull << l) - 1ull));
            if (alive) {
                if (rank < DETS) {
                    float* o = obox + rank * 5;
                    o[0] = tb[0][l]; o[1] = tb[1][l]; o[2] = tb[2][l]; o[3] = tb[3][l];
                    o[4] = tb[5][l];
                    olab[rank] = 1.0f;
                    oval[rank] = 1.0f;
                }
                kb[0][rank] = tb[0][l]; kb[1][rank] = tb[1][l];
                kb[2][rank] = tb[2][l]; kb[3][rank] = tb[3][l];
                kb[4][rank] = tb[4][l];
            }
            if (l == 0) keptCount = kept + (int)__popcll(am);
        }
        __syncthreads();
        kept = keptCount;
    }

    // ---------------- zero-fill remaining output rows ----------------
    int start = kept < DETS ? kept : DETS;
    for (int c = start + tid; c < DETS; c += NTHREADS) {
        float* o = obox + c * 5;
        o[0] = 0.0f; o[1] = 0.0f; o[2] = 0.0f; o[3] = 0.0f; o[4] = 0.0f;
        olab[c] = 0.0f;
        oval[c] = 0.0f;
    }
}

extern "C" void kernel_launch(void* const* d_in, const int* in_sizes, int n_in,
                              void* d_out, int out_size, void* d_ws, size_t ws_size,
                              hipStream_t stream) {
    (void)d_ws; (void)ws_size; (void)n_in;
    const float* logits = (const float*)d_in[0];
    const float* regr   = (const float*)d_in[1];
    const float* props  = (const float*)d_in[2];
    float* out = (float*)d_out;

    int B = out_size / 700;          // (100*5 + 100 + 100) per image
    if (B < 1) B = 1;
    int N = in_sizes[0] / (2 * B);   // logits = B*N*2

    postproc_kernel<<<B, NTHREADS, 0, stream>>>(logits, regr, props, out, B, N);
}